// Round 4
// baseline (3002.508 us; speedup 1.0000x reference)
//
#include <hip/hip_runtime.h>
#include <hip/hip_bf16.h>

#define N_NODES 100000
#define E_EDGES 600000
#define HDIM 128
#define H2DIM 256
#define NLAYER 3
#define NSUBT 2
#define NSUB_G 20000
#define ESUB_E 200000
#define OUTD 128

typedef __bf16 bf16_t;
typedef __bf16 bf16x8 __attribute__((ext_vector_type(8)));
typedef __bf16 bf16x4 __attribute__((ext_vector_type(4)));
typedef __bf16 bf16x2 __attribute__((ext_vector_type(2)));
typedef float f32x4 __attribute__((ext_vector_type(4)));
typedef float f32x2 __attribute__((ext_vector_type(2)));

// async global->LDS, 16B per lane; LDS dest = wave-uniform base + lane*16
#define GLOAD_LDS16(gp, lp)                                                      \
    __builtin_amdgcn_global_load_lds(                                            \
        (const __attribute__((address_space(1))) void*)(gp),                     \
        (__attribute__((address_space(3))) void*)(lp), 16, 0, 0)

// ---------------------------------------------------------------------------
// Weight transpose: W[k][n] (row-major K x Nc, fp32) -> Wt[n][k] (bf16)
// ---------------------------------------------------------------------------
__global__ __launch_bounds__(256) void transpose_w(const float* __restrict__ W,
                                                   bf16_t* __restrict__ Wt,
                                                   int K, int Nc, long total) {
    long idx = (long)blockIdx.x * 256 + threadIdx.x;
    if (idx >= total) return;
    long kn = (long)K * Nc;
    long b = idx / kn;
    long r = idx - b * kn;
    int k = (int)(r / Nc);
    int n = (int)(r - (long)k * Nc);
    Wt[b * kn + (long)n * K + k] = (bf16_t)W[idx];
}

__global__ __launch_bounds__(256) void cast_f2b(const float* __restrict__ in,
                                                bf16_t* __restrict__ out, long n) {
    long i = ((long)blockIdx.x * 256 + threadIdx.x) * 4;
    if (i >= n) return;
    f32x4 v = *(const f32x4*)(in + i);
    bf16x4 o;
    o[0] = (bf16_t)v[0]; o[1] = (bf16_t)v[1];
    o[2] = (bf16_t)v[2]; o[3] = (bf16_t)v[3];
    *(bf16x4*)(out + i) = o;
}

// ---------------------------------------------------------------------------
// CSR build: histogram -> hierarchical exclusive scan -> placement
// ---------------------------------------------------------------------------
__global__ __launch_bounds__(256) void hist_k(const int* __restrict__ idx,
                                              int* __restrict__ counts, int nE) {
    int e = blockIdx.x * 256 + threadIdx.x;
    if (e < nE) atomicAdd(&counts[idx[e]], 1);
}

__global__ __launch_bounds__(256) void scan1_k(const int* __restrict__ in,
                                               int* __restrict__ out,
                                               int* __restrict__ bsum, int n) {
    __shared__ int tmp[256];
    const int t = threadIdx.x;
    const long base = (long)blockIdx.x * 1024 + (long)t * 4;
    int v[4];
    int s = 0;
#pragma unroll
    for (int j = 0; j < 4; j++) {
        long i = base + j;
        int x = (i < n) ? in[i] : 0;
        v[j] = s;
        s += x;
    }
    tmp[t] = s;
    __syncthreads();
    int inc = s;
    for (int off = 1; off < 256; off <<= 1) {
        int y = (t >= off) ? tmp[t - off] : 0;
        __syncthreads();
        inc += y;
        tmp[t] = inc;
        __syncthreads();
    }
    const int toff = inc - s;
#pragma unroll
    for (int j = 0; j < 4; j++) {
        long i = base + j;
        if (i < n) out[i] = v[j] + toff;
    }
    if (t == 255) bsum[blockIdx.x] = inc;
}

__global__ __launch_bounds__(256) void scan2_k(int* __restrict__ bsum, int nb) {
    __shared__ int tmp[256];
    const int t = threadIdx.x;
    int x = (t < nb) ? bsum[t] : 0;
    tmp[t] = x;
    __syncthreads();
    int inc = x;
    for (int off = 1; off < 256; off <<= 1) {
        int y = (t >= off) ? tmp[t - off] : 0;
        __syncthreads();
        inc += y;
        tmp[t] = inc;
        __syncthreads();
    }
    if (t < nb) bsum[t] = inc - x;
}

__global__ __launch_bounds__(256) void scan3_k(const int* __restrict__ partial,
                                               const int* __restrict__ bsum,
                                               int* __restrict__ rowptr,
                                               int* __restrict__ work,
                                               int n, int total) {
    long i = (long)blockIdx.x * 256 + threadIdx.x;
    if (i < n) {
        int v = partial[i] + bsum[i >> 10];
        rowptr[i] = v;
        work[i] = v;
    }
    if (i == 0) rowptr[n] = total;
}

__global__ __launch_bounds__(256) void csr_place(const int* __restrict__ idx,
                                                 const int* __restrict__ gsrc,
                                                 int* __restrict__ work,
                                                 int* __restrict__ gat, int nE) {
    int e = blockIdx.x * 256 + threadIdx.x;
    if (e < nE) {
        int p = atomicAdd(&work[idx[e]], 1);
        gat[p] = gsrc[e];
    }
}

// ---------------------------------------------------------------------------
// Gather-based segment sums over bf16 features (one wave per segment).
// ---------------------------------------------------------------------------
__global__ __launch_bounds__(256) void segsum_ginb(const bf16_t* __restrict__ X,
                                                   const float* __restrict__ epsPtr,
                                                   const int* __restrict__ rowptr,
                                                   const int* __restrict__ gat,
                                                   bf16_t* __restrict__ out, int nseg) {
    int seg = blockIdx.x * 4 + (threadIdx.x >> 6);
    if (seg >= nseg) return;
    int lane = threadIdx.x & 63;
    float alpha = 1.f + epsPtr[0];
    bf16x2 xv = *((const bf16x2*)(X + (size_t)seg * HDIM) + lane);
    float a0 = alpha * (float)xv[0], a1 = alpha * (float)xv[1];
    int s0 = rowptr[seg], s1 = rowptr[seg + 1];
    for (int e = s0; e < s1; e++) {
        int g = gat[e];
        bf16x2 v = *((const bf16x2*)(X + (size_t)g * HDIM) + lane);
        a0 += (float)v[0];
        a1 += (float)v[1];
    }
    bf16x2 o;
    o[0] = (bf16_t)a0;
    o[1] = (bf16_t)a1;
    *((bf16x2*)(out + (size_t)seg * HDIM) + lane) = o;
}

__global__ __launch_bounds__(256) void segsum_b16(const bf16_t* __restrict__ X,
                                                  const int* __restrict__ rowptr,
                                                  const int* __restrict__ gat,
                                                  bf16_t* __restrict__ out, int nseg) {
    int seg = blockIdx.x * 4 + (threadIdx.x >> 6);
    if (seg >= nseg) return;
    int lane = threadIdx.x & 63;
    float a0 = 0.f, a1 = 0.f;
    int s0 = rowptr[seg], s1 = rowptr[seg + 1];
    for (int e = s0; e < s1; e++) {
        int g = gat[e];
        bf16x2 v = *((const bf16x2*)(X + (size_t)g * HDIM) + lane);
        a0 += (float)v[0];
        a1 += (float)v[1];
    }
    bf16x2 o;
    o[0] = (bf16_t)a0;
    o[1] = (bf16_t)a1;
    *((bf16x2*)(out + (size_t)seg * HDIM) + lane) = o;
}

// ---------------------------------------------------------------------------
// BN finalize
// ---------------------------------------------------------------------------
__global__ void bn_finalize(const float* __restrict__ cs, const float* __restrict__ cs2,
                            const float* __restrict__ g, const float* __restrict__ b,
                            float* __restrict__ scale, float* __restrict__ shift,
                            int C, float invN) {
    int c = blockIdx.x * blockDim.x + threadIdx.x;
    if (c >= C) return;
    float m = cs[c] * invN;
    float v = cs2[c] * invN - m * m;
    float sc = g[c] * rsqrtf(v + 1e-5f);
    scale[c] = sc;
    shift[c] = b[c] - m * sc;
}

// ---------------------------------------------------------------------------
// Full-weight-resident GEMM: the ENTIRE weight (K x NC = 64KB bf16) lives in
// LDS (staged once per block, XOR-swizzled). Block = 4 waves x 32 rows = 128
// rows, each wave computes 32 x NC. A-fragments are loaded directly from
// global (row-major bf16: one dwordx4 per frag, 64B-segment coalesced), all
// issued upfront -> deep memory-level parallelism, no K-loop barriers.
// bnfold: A := relu(A*bnScale[k]+bnShift[k]) before MFMA (BN fold).
// flags: 1 relu, 2 accumulate (bf16 RMW on outB), 4 column stats.
// outF non-null => fp32 store (final output), else bf16 store to outB.
// ---------------------------------------------------------------------------
template <int K, int NC>
__global__ __launch_bounds__(256) void gemm_full(
    const bf16_t* __restrict__ Ab,
    const float* __restrict__ bnScale, const float* __restrict__ bnShift,
    const bf16_t* __restrict__ Wt, const float* __restrict__ bias,
    int M,
    bf16_t* __restrict__ outB, float* __restrict__ outF,
    float* __restrict__ colsum, float* __restrict__ colsumsq,
    int bnfold, int flags) {
    constexpr int KC = K / 8;    // 16B chunks per weight row
    constexpr int NKS = K / 32;  // k-steps
    constexpr int NNI = NC / 16; // n-frags
    __shared__ bf16_t lB[NC * K];  // 64 KB exactly
    const int tid = threadIdx.x;
    const int w = tid >> 6, lane = tid & 63;
    const int q = lane >> 4, lm = lane & 15;

    // ---- stage whole weight into LDS, swizzled: lB[n][c] = Wt[n][c^(n&7)] ----
    constexpr int ROUNDS = (NC * K * 2) / (256 * 16);  // 16
#pragma unroll
    for (int rnd = 0; rnd < ROUNDS; rnd++) {
        const int slot = rnd * 256 + tid;        // 16B slot id = n*KC + c
        const int n = slot / KC;
        const int c = slot - n * KC;
        const int src = (c & ~7) | ((c & 7) ^ (n & 7));
        GLOAD_LDS16(Wt + (size_t)n * K + src * 8,
                    lB + (size_t)(rnd * 256 + w * 64) * 8);
    }

    // ---- load all A-fragments for this row tile (direct from global) ----
    const int row0 = blockIdx.x * 128 + w * 32;
    bf16x8 af[2][NKS];
#pragma unroll
    for (int mi = 0; mi < 2; mi++) {
        int gr = row0 + mi * 16 + lm;
        if (gr > M - 1) gr = M - 1;
        const bf16_t* ap = Ab + (size_t)gr * K + q * 8;
#pragma unroll
        for (int ks = 0; ks < NKS; ks++)
            af[mi][ks] = *(const bf16x8*)(ap + ks * 32);
    }
    if (bnfold) {
#pragma unroll
        for (int ks = 0; ks < NKS; ks++) {
            const int kk = ks * 32 + q * 8;
            f32x4 s0 = ((const f32x4*)(bnScale + kk))[0];
            f32x4 s1v = ((const f32x4*)(bnScale + kk))[1];
            f32x4 h0 = ((const f32x4*)(bnShift + kk))[0];
            f32x4 h1 = ((const f32x4*)(bnShift + kk))[1];
            float sc8[8] = {s0[0], s0[1], s0[2], s0[3], s1v[0], s1v[1], s1v[2], s1v[3]};
            float sh8[8] = {h0[0], h0[1], h0[2], h0[3], h1[0], h1[1], h1[2], h1[3]};
#pragma unroll
            for (int mi = 0; mi < 2; mi++)
#pragma unroll
                for (int j = 0; j < 8; j++) {
                    float f = fmaxf((float)af[mi][ks][j] * sc8[j] + sh8[j], 0.f);
                    af[mi][ks][j] = (bf16_t)f;
                }
        }
    }

    __builtin_amdgcn_s_waitcnt(0);  // drain global_load_lds
    __syncthreads();

    // ---- K-loop: B-frags from LDS, no barriers ----
    f32x4 acc[2][NNI];
#pragma unroll
    for (int a = 0; a < 2; a++)
#pragma unroll
        for (int b = 0; b < NNI; b++) acc[a][b] = f32x4{0.f, 0.f, 0.f, 0.f};
#pragma unroll
    for (int ks = 0; ks < NKS; ks++) {
#pragma unroll
        for (int ni = 0; ni < NNI; ni++) {
            const int n = ni * 16 + lm;
            const int c = (ks * 4 + q) ^ (n & 7);
            bf16x8 bf = *(const bf16x8*)(lB + (size_t)n * K + c * 8);
            acc[0][ni] = __builtin_amdgcn_mfma_f32_16x16x32_bf16(af[0][ks], bf, acc[0][ni], 0, 0, 0);
            acc[1][ni] = __builtin_amdgcn_mfma_f32_16x16x32_bf16(af[1][ks], bf, acc[1][ni], 0, 0, 0);
        }
    }

    // ---- epilogue ----
    const bool doRelu = (flags & 1), doAccum = (flags & 2), doStats = (flags & 4);
#pragma unroll
    for (int ni = 0; ni < NNI; ni++) {
        const int col = ni * 16 + lm;
        const float bv = bias[col];
        float s1 = 0.f, s2 = 0.f;
#pragma unroll
        for (int mi = 0; mi < 2; mi++) {
#pragma unroll
            for (int r = 0; r < 4; r++) {
                const int row = row0 + mi * 16 + q * 4 + r;
                if (row < M) {
                    float v = acc[mi][ni][r] + bv;
                    if (doStats) { s1 += v; s2 += v * v; }
                    if (doRelu) v = fmaxf(v, 0.f);
                    const size_t o = (size_t)row * NC + col;
                    if (outF) {
                        outF[o] = v;
                    } else {
                        if (doAccum) v += (float)outB[o];
                        outB[o] = (bf16_t)v;
                    }
                }
            }
        }
        if (doStats) {
            s1 += __shfl_xor(s1, 16);
            s1 += __shfl_xor(s1, 32);
            s2 += __shfl_xor(s2, 16);
            s2 += __shfl_xor(s2, 32);
            if (q == 0) {
                atomicAdd(&colsum[col], s1);
                atomicAdd(&colsumsq[col], s2);
            }
        }
    }
}

// ---------------------------------------------------------------------------
extern "C" void kernel_launch(void* const* d_in, const int* in_sizes, int n_in,
                              void* d_out, int out_size, void* d_ws, size_t ws_size,
                              hipStream_t stream) {
    const float* x_in   = (const float*)d_in[0];
    const int*   ei     = (const int*)d_in[1];
    const int*   se0    = (const int*)d_in[2];
    const int*   se1    = (const int*)d_in[3];
    const float* msg_w1 = (const float*)d_in[4];
    const float* msg_b1 = (const float*)d_in[5];
    const float* bn_g   = (const float*)d_in[6];
    const float* bn_b   = (const float*)d_in[7];
    const float* msg_w2 = (const float*)d_in[8];
    const float* msg_b2 = (const float*)d_in[9];
    const float* eps_g  = (const float*)d_in[10];
    const float* n2s_w1 = (const float*)d_in[11];
    const float* n2s_b1 = (const float*)d_in[12];
    const float* n2s_w2 = (const float*)d_in[13];
    const float* n2s_b2 = (const float*)d_in[14];
    const float* s2n_w1 = (const float*)d_in[15];
    const float* s2n_b1 = (const float*)d_in[16];
    const float* s2n_w2 = (const float*)d_in[17];
    const float* s2n_b2 = (const float*)d_in[18];
    const float* out_w1 = (const float*)d_in[19];
    const float* out_b1 = (const float*)d_in[20];
    const float* out_w2 = (const float*)d_in[21];
    const float* out_b2 = (const float*)d_in[22];
    float* out = (float*)d_out;

    char* ws = (char*)d_ws;
    size_t off = 0;
    auto alloc = [&](size_t bytes) -> char* {
        char* p = ws + off;
        off += (bytes + 255) & ~(size_t)255;
        return p;
    };
    bf16_t* xbf   = (bf16_t*)alloc((size_t)N_NODES * HDIM * 2);   // residual x (bf16)
    bf16_t* xcomb = (bf16_t*)alloc((size_t)N_NODES * HDIM * 2);   // gin-comb / s2n msg
    bf16_t* hbuf  = (bf16_t*)alloc((size_t)N_NODES * H2DIM * 2);
    bf16_t* sxsum = (bf16_t*)alloc((size_t)NSUB_G * HDIM * 2);
    bf16_t* shbuf = (bf16_t*)alloc((size_t)NSUB_G * H2DIM * 2);
    bf16_t* sxout = (bf16_t*)alloc((size_t)NSUB_G * HDIM * 2);
    const size_t WSZ = (size_t)HDIM * H2DIM;
    bf16_t* wt_msg1 = (bf16_t*)alloc(NLAYER * WSZ * 2);
    bf16_t* wt_msg2 = (bf16_t*)alloc(NLAYER * WSZ * 2);
    bf16_t* wt_n2s1 = (bf16_t*)alloc(NLAYER * NSUBT * WSZ * 2);
    bf16_t* wt_n2s2 = (bf16_t*)alloc(NLAYER * NSUBT * WSZ * 2);
    bf16_t* wt_s2n1 = (bf16_t*)alloc(NLAYER * NSUBT * WSZ * 2);
    bf16_t* wt_s2n2 = (bf16_t*)alloc(NLAYER * NSUBT * WSZ * 2);
    bf16_t* wt_out1 = (bf16_t*)alloc(WSZ * 2);
    bf16_t* wt_out2 = (bf16_t*)alloc(WSZ * 2);
    float* colsum   = (float*)alloc(H2DIM * 4);
    float* colsumsq = (float*)alloc(H2DIM * 4);
    float* bnscale  = (float*)alloc(H2DIM * 4);
    float* bnshift  = (float*)alloc(H2DIM * 4);
    int* rp_gin   = (int*)alloc((N_NODES + 1) * 4);
    int* gat_gin  = (int*)alloc((size_t)E_EDGES * 4);
    int* rp_n2s0  = (int*)alloc((NSUB_G + 1) * 4);
    int* gat_n2s0 = (int*)alloc((size_t)ESUB_E * 4);
    int* rp_n2s1  = (int*)alloc((NSUB_G + 1) * 4);
    int* gat_n2s1 = (int*)alloc((size_t)ESUB_E * 4);
    int* rp_s2n0  = (int*)alloc((N_NODES + 1) * 4);
    int* gat_s2n0 = (int*)alloc((size_t)ESUB_E * 4);
    int* rp_s2n1  = (int*)alloc((N_NODES + 1) * 4);
    int* gat_s2n1 = (int*)alloc((size_t)ESUB_E * 4);
    int* counts  = (int*)alloc((N_NODES + 1) * 4);
    int* partial = (int*)alloc((size_t)N_NODES * 4);
    int* bsum    = (int*)alloc(512 * 4);
    (void)ws_size; (void)in_sizes; (void)n_in; (void)out_size;

    auto tr = [&](const float* W, bf16_t* Wt, int K, int Nc, int batch) {
        long total = (long)batch * K * Nc;
        int blocks = (int)((total + 255) / 256);
        transpose_w<<<blocks, 256, 0, stream>>>(W, Wt, K, Nc, total);
    };
    tr(msg_w1, wt_msg1, HDIM, H2DIM, NLAYER);
    tr(msg_w2, wt_msg2, H2DIM, HDIM, NLAYER);
    tr(n2s_w1, wt_n2s1, HDIM, H2DIM, NLAYER * NSUBT);
    tr(n2s_w2, wt_n2s2, H2DIM, HDIM, NLAYER * NSUBT);
    tr(s2n_w1, wt_s2n1, HDIM, H2DIM, NLAYER * NSUBT);
    tr(s2n_w2, wt_s2n2, H2DIM, HDIM, NLAYER * NSUBT);
    tr(out_w1, wt_out1, HDIM, H2DIM, 1);
    tr(out_w2, wt_out2, H2DIM, OUTD, 1);

    auto build_csr = [&](const int* idx, const int* gsrc, int nE, int nseg,
                         int* rowptr, int* gat) {
        hipMemsetAsync(counts, 0, (size_t)nseg * 4, stream);
        hist_k<<<(nE + 255) / 256, 256, 0, stream>>>(idx, counts, nE);
        int nb = (nseg + 1023) / 1024;
        scan1_k<<<nb, 256, 0, stream>>>(counts, partial, bsum, nseg);
        scan2_k<<<1, 256, 0, stream>>>(bsum, nb);
        scan3_k<<<(nseg + 255) / 256, 256, 0, stream>>>(partial, bsum, rowptr,
                                                        counts, nseg, nE);
        csr_place<<<(nE + 255) / 256, 256, 0, stream>>>(idx, gsrc, counts, gat, nE);
    };
    const int* src = ei;
    const int* dst = ei + E_EDGES;
    build_csr(dst, src, E_EDGES, N_NODES, rp_gin, gat_gin);
    build_csr(se0 + ESUB_E, se0, ESUB_E, NSUB_G, rp_n2s0, gat_n2s0);
    build_csr(se1 + ESUB_E, se1, ESUB_E, NSUB_G, rp_n2s1, gat_n2s1);
    build_csr(se0, se0 + ESUB_E, ESUB_E, N_NODES, rp_s2n0, gat_s2n0);
    build_csr(se1, se1 + ESUB_E, ESUB_E, N_NODES, rp_s2n1, gat_s2n1);

    {
        long n = (long)N_NODES * HDIM;
        cast_f2b<<<(int)((n / 4 + 255) / 256), 256, 0, stream>>>(x_in, xbf, n);
    }

    // gemm wrappers: K/NC are compile-time (128,256) or (256,128)
    auto gemmA = [&](const bf16_t* Ab, const float* bnS, const float* bnH,
                     const bf16_t* Wt, const float* bias, int M,
                     bf16_t* oB, float* oF, float* cs, float* cs2,
                     int bnfold, int flags) {  // K=128, NC=256
        gemm_full<128, 256><<<(M + 127) / 128, 256, 0, stream>>>(
            Ab, bnS, bnH, Wt, bias, M, oB, oF, cs, cs2, bnfold, flags);
    };
    auto gemmB = [&](const bf16_t* Ab, const float* bnS, const float* bnH,
                     const bf16_t* Wt, const float* bias, int M,
                     bf16_t* oB, float* oF, float* cs, float* cs2,
                     int bnfold, int flags) {  // K=256, NC=128
        gemm_full<256, 128><<<(M + 127) / 128, 256, 0, stream>>>(
            Ab, bnS, bnH, Wt, bias, M, oB, oF, cs, cs2, bnfold, flags);
    };

    for (int i = 0; i < NLAYER; i++) {
        // GIN aggregation fused with (1+eps)x combine -> bf16
        segsum_ginb<<<(N_NODES + 3) / 4, 256, 0, stream>>>(
            xbf, eps_g + i, rp_gin, gat_gin, xcomb, N_NODES);
        // h = xcomb @ W1 + b1 ; column stats for BN
        hipMemsetAsync(colsum, 0, H2DIM * 4, stream);
        hipMemsetAsync(colsumsq, 0, H2DIM * 4, stream);
        gemmA(xcomb, nullptr, nullptr,
              wt_msg1 + (size_t)i * WSZ, msg_b1 + (size_t)i * H2DIM,
              N_NODES, hbuf, nullptr, colsum, colsumsq, 0, 4);
        bn_finalize<<<1, 256, 0, stream>>>(colsum, colsumsq, bn_g + (size_t)i * H2DIM,
                                           bn_b + (size_t)i * H2DIM, bnscale, bnshift,
                                           H2DIM, 1.0f / N_NODES);
        // x = relu(BN(h)) @ W2 + b2   (bf16)
        gemmB(hbuf, bnscale, bnshift,
              wt_msg2 + (size_t)i * WSZ, msg_b2 + (size_t)i * HDIM,
              N_NODES, xbf, nullptr, nullptr, nullptr, 1, 0);

        for (int s = 0; s < NSUBT; s++) {
            const int* rp_n2s = (s == 0 ? rp_n2s0 : rp_n2s1);
            const int* gt_n2s = (s == 0 ? gat_n2s0 : gat_n2s1);
            const int* rp_s2n = (s == 0 ? rp_s2n0 : rp_s2n1);
            const int* gt_s2n = (s == 0 ? gat_s2n0 : gat_s2n1);
            const size_t widx = ((size_t)i * NSUBT + s) * WSZ;
            const size_t b1o = ((size_t)i * NSUBT + s) * H2DIM;
            const size_t b2o = ((size_t)i * NSUBT + s) * HDIM;
            // sx = segment_sum(x[row], col)
            segsum_b16<<<(NSUB_G + 3) / 4, 256, 0, stream>>>(
                xbf, rp_n2s, gt_n2s, sxsum, NSUB_G);
            // sx = relu(sx@w1+b1)@w2+b2
            gemmA(sxsum, nullptr, nullptr, wt_n2s1 + widx, n2s_b1 + b1o,
                  NSUB_G, shbuf, nullptr, nullptr, nullptr, 0, 1);
            gemmB(shbuf, nullptr, nullptr, wt_n2s2 + widx, n2s_b2 + b2o,
                  NSUB_G, sxout, nullptr, nullptr, nullptr, 0, 0);
            // msg = segment_sum(sx[col], row)
            segsum_b16<<<(N_NODES + 3) / 4, 256, 0, stream>>>(
                sxout, rp_s2n, gt_s2n, xcomb, N_NODES);
            // x += relu(msg@w1+b1)@w2+b2
            gemmA(xcomb, nullptr, nullptr, wt_s2n1 + widx, s2n_b1 + b1o,
                  N_NODES, hbuf, nullptr, nullptr, nullptr, 0, 1);
            gemmB(hbuf, nullptr, nullptr, wt_s2n2 + widx, s2n_b2 + b2o,
                  N_NODES, xbf, nullptr, nullptr, nullptr, 0, 2);
        }
    }
    // output head
    gemmA(xbf, nullptr, nullptr, wt_out1, out_b1,
          N_NODES, hbuf, nullptr, nullptr, nullptr, 0, 1);
    gemmB(hbuf, nullptr, nullptr, wt_out2, out_b2,
          N_NODES, nullptr, out, nullptr, nullptr, 0, 0);
}

// Round 5
// 2196.059 us; speedup vs baseline: 1.3672x; 1.3672x over previous
//
#include <hip/hip_runtime.h>
#include <hip/hip_bf16.h>

#define N_NODES 100000
#define E_EDGES 600000
#define HDIM 128
#define H2DIM 256
#define NLAYER 3
#define NSUBT 2
#define NSUB_G 20000
#define ESUB_E 200000
#define OUTD 128
#define NBLK 768  // persistent-GEMM grid: 3 blocks/CU

typedef __bf16 bf16_t;
typedef __bf16 bf16x8 __attribute__((ext_vector_type(8)));
typedef __bf16 bf16x4 __attribute__((ext_vector_type(4)));
typedef __bf16 bf16x2 __attribute__((ext_vector_type(2)));
typedef float f32x4 __attribute__((ext_vector_type(4)));
typedef float f32x2 __attribute__((ext_vector_type(2)));

// ---------------------------------------------------------------------------
// Weight transpose: W[k][n] (row-major K x Nc, fp32) -> Wt[n][k] (bf16)
// ---------------------------------------------------------------------------
__global__ __launch_bounds__(256) void transpose_w(const float* __restrict__ W,
                                                   bf16_t* __restrict__ Wt,
                                                   int K, int Nc, long total) {
    long idx = (long)blockIdx.x * 256 + threadIdx.x;
    if (idx >= total) return;
    long kn = (long)K * Nc;
    long b = idx / kn;
    long r = idx - b * kn;
    int k = (int)(r / Nc);
    int n = (int)(r - (long)k * Nc);
    Wt[b * kn + (long)n * K + k] = (bf16_t)W[idx];
}

__global__ __launch_bounds__(256) void cast_f2b(const float* __restrict__ in,
                                                bf16_t* __restrict__ out, long n) {
    long i = ((long)blockIdx.x * 256 + threadIdx.x) * 4;
    if (i >= n) return;
    f32x4 v = *(const f32x4*)(in + i);
    bf16x4 o;
    o[0] = (bf16_t)v[0]; o[1] = (bf16_t)v[1];
    o[2] = (bf16_t)v[2]; o[3] = (bf16_t)v[3];
    *(bf16x4*)(out + i) = o;
}

// ---------------------------------------------------------------------------
// CSR build: histogram -> hierarchical exclusive scan -> placement
// ---------------------------------------------------------------------------
__global__ __launch_bounds__(256) void hist_k(const int* __restrict__ idx,
                                              int* __restrict__ counts, int nE) {
    int e = blockIdx.x * 256 + threadIdx.x;
    if (e < nE) atomicAdd(&counts[idx[e]], 1);
}

__global__ __launch_bounds__(256) void scan1_k(const int* __restrict__ in,
                                               int* __restrict__ out,
                                               int* __restrict__ bsum, int n) {
    __shared__ int tmp[256];
    const int t = threadIdx.x;
    const long base = (long)blockIdx.x * 1024 + (long)t * 4;
    int v[4];
    int s = 0;
#pragma unroll
    for (int j = 0; j < 4; j++) {
        long i = base + j;
        int x = (i < n) ? in[i] : 0;
        v[j] = s;
        s += x;
    }
    tmp[t] = s;
    __syncthreads();
    int inc = s;
    for (int off = 1; off < 256; off <<= 1) {
        int y = (t >= off) ? tmp[t - off] : 0;
        __syncthreads();
        inc += y;
        tmp[t] = inc;
        __syncthreads();
    }
    const int toff = inc - s;
#pragma unroll
    for (int j = 0; j < 4; j++) {
        long i = base + j;
        if (i < n) out[i] = v[j] + toff;
    }
    if (t == 255) bsum[blockIdx.x] = inc;
}

__global__ __launch_bounds__(256) void scan2_k(int* __restrict__ bsum, int nb) {
    __shared__ int tmp[256];
    const int t = threadIdx.x;
    int x = (t < nb) ? bsum[t] : 0;
    tmp[t] = x;
    __syncthreads();
    int inc = x;
    for (int off = 1; off < 256; off <<= 1) {
        int y = (t >= off) ? tmp[t - off] : 0;
        __syncthreads();
        inc += y;
        tmp[t] = inc;
        __syncthreads();
    }
    if (t < nb) bsum[t] = inc - x;
}

__global__ __launch_bounds__(256) void scan3_k(const int* __restrict__ partial,
                                               const int* __restrict__ bsum,
                                               int* __restrict__ rowptr,
                                               int* __restrict__ work,
                                               int n, int total) {
    long i = (long)blockIdx.x * 256 + threadIdx.x;
    if (i < n) {
        int v = partial[i] + bsum[i >> 10];
        rowptr[i] = v;
        work[i] = v;
    }
    if (i == 0) rowptr[n] = total;
}

__global__ __launch_bounds__(256) void csr_place(const int* __restrict__ idx,
                                                 const int* __restrict__ gsrc,
                                                 int* __restrict__ work,
                                                 int* __restrict__ gat, int nE) {
    int e = blockIdx.x * 256 + threadIdx.x;
    if (e < nE) {
        int p = atomicAdd(&work[idx[e]], 1);
        gat[p] = gsrc[e];
    }
}

// ---------------------------------------------------------------------------
// Gather-based segment sums over bf16 features (one wave per segment).
// ---------------------------------------------------------------------------
__global__ __launch_bounds__(256) void segsum_ginb(const bf16_t* __restrict__ X,
                                                   const float* __restrict__ epsPtr,
                                                   const int* __restrict__ rowptr,
                                                   const int* __restrict__ gat,
                                                   bf16_t* __restrict__ out, int nseg) {
    int seg = blockIdx.x * 4 + (threadIdx.x >> 6);
    if (seg >= nseg) return;
    int lane = threadIdx.x & 63;
    float alpha = 1.f + epsPtr[0];
    bf16x2 xv = *((const bf16x2*)(X + (size_t)seg * HDIM) + lane);
    float a0 = alpha * (float)xv[0], a1 = alpha * (float)xv[1];
    int s0 = rowptr[seg], s1 = rowptr[seg + 1];
    for (int e = s0; e < s1; e++) {
        int g = gat[e];
        bf16x2 v = *((const bf16x2*)(X + (size_t)g * HDIM) + lane);
        a0 += (float)v[0];
        a1 += (float)v[1];
    }
    bf16x2 o;
    o[0] = (bf16_t)a0;
    o[1] = (bf16_t)a1;
    *((bf16x2*)(out + (size_t)seg * HDIM) + lane) = o;
}

__global__ __launch_bounds__(256) void segsum_b16(const bf16_t* __restrict__ X,
                                                  const int* __restrict__ rowptr,
                                                  const int* __restrict__ gat,
                                                  bf16_t* __restrict__ out, int nseg) {
    int seg = blockIdx.x * 4 + (threadIdx.x >> 6);
    if (seg >= nseg) return;
    int lane = threadIdx.x & 63;
    float a0 = 0.f, a1 = 0.f;
    int s0 = rowptr[seg], s1 = rowptr[seg + 1];
    for (int e = s0; e < s1; e++) {
        int g = gat[e];
        bf16x2 v = *((const bf16x2*)(X + (size_t)g * HDIM) + lane);
        a0 += (float)v[0];
        a1 += (float)v[1];
    }
    bf16x2 o;
    o[0] = (bf16_t)a0;
    o[1] = (bf16_t)a1;
    *((bf16x2*)(out + (size_t)seg * HDIM) + lane) = o;
}

// ---------------------------------------------------------------------------
// BN finalize
// ---------------------------------------------------------------------------
__global__ void bn_finalize(const float* __restrict__ cs, const float* __restrict__ cs2,
                            const float* __restrict__ g, const float* __restrict__ b,
                            float* __restrict__ scale, float* __restrict__ shift,
                            int C, float invN) {
    int c = blockIdx.x * blockDim.x + threadIdx.x;
    if (c >= C) return;
    float m = cs[c] * invN;
    float v = cs2[c] * invN - m * m;
    float sc = g[c] * rsqrtf(v + 1e-5f);
    scale[c] = sc;
    shift[c] = b[c] - m * sc;
}

// ---------------------------------------------------------------------------
// Register-resident-weight persistent GEMM. No LDS, no barriers.
// Each wave owns a NC/4-column slice of W as NNI*NKS b-fragments held in
// VGPRs for the whole kernel, and processes 32-row tiles in a grid-strided
// loop (4 waves of a block share the same rows -> A-loads hit L1).
// bnfold: A := relu(A*bnScale[k]+bnShift[k]) before MFMA (BN fold).
// flags: 1 relu, 2 accumulate (bf16 RMW on outB), 4 column stats.
// outF non-null => fp32 store (final output), else bf16 store to outB.
// ---------------------------------------------------------------------------
template <int K, int NC>
__global__ __launch_bounds__(256, 3) void gemm_reg(
    const bf16_t* __restrict__ Ab,
    const float* __restrict__ bnScale, const float* __restrict__ bnShift,
    const bf16_t* __restrict__ Wt, const float* __restrict__ bias,
    int M,
    bf16_t* __restrict__ outB, float* __restrict__ outF,
    float* __restrict__ colsum, float* __restrict__ colsumsq,
    int bnfold, int flags) {
    constexpr int NKS = K / 32;       // k-steps (4 or 8)
    constexpr int SLICE = NC / 4;     // cols per wave (64 or 32)
    constexpr int NNI = SLICE / 16;   // n-frags per wave (4 or 2)
    const int w = threadIdx.x >> 6, lane = threadIdx.x & 63;
    const int q = lane >> 4, lm = lane & 15;
    const int c0 = w * SLICE;

    // resident B-fragments (NNI*NKS = 16 frags = 64 VGPRs)
    bf16x8 bfr[NNI][NKS];
#pragma unroll
    for (int ni = 0; ni < NNI; ni++) {
        const bf16_t* bp = Wt + (size_t)(c0 + ni * 16 + lm) * K + q * 8;
#pragma unroll
        for (int ks = 0; ks < NKS; ks++)
            bfr[ni][ks] = *(const bf16x8*)(bp + ks * 32);
    }
    const bool doRelu = (flags & 1), doAccum = (flags & 2), doStats = (flags & 4);
    float bv[NNI];
#pragma unroll
    for (int ni = 0; ni < NNI; ni++) bv[ni] = bias[c0 + ni * 16 + lm];
    float st1[NNI], st2[NNI];
#pragma unroll
    for (int ni = 0; ni < NNI; ni++) { st1[ni] = 0.f; st2[ni] = 0.f; }

    const int nTiles = (M + 31) >> 5;
    for (int t = blockIdx.x; t < nTiles; t += gridDim.x) {
        const int row0 = t << 5;
        bf16x8 af[2][NKS];
#pragma unroll
        for (int mi = 0; mi < 2; mi++) {
            int gr = row0 + mi * 16 + lm;
            if (gr > M - 1) gr = M - 1;  // clamp; stores/stats guarded
            const bf16_t* ap = Ab + (size_t)gr * K + q * 8;
#pragma unroll
            for (int ks = 0; ks < NKS; ks++)
                af[mi][ks] = *(const bf16x8*)(ap + ks * 32);
        }
        if (bnfold) {
#pragma unroll
            for (int ks = 0; ks < NKS; ks++) {
                const int kk = ks * 32 + q * 8;
                f32x4 s0 = ((const f32x4*)(bnScale + kk))[0];
                f32x4 s1v = ((const f32x4*)(bnScale + kk))[1];
                f32x4 h0 = ((const f32x4*)(bnShift + kk))[0];
                f32x4 h1 = ((const f32x4*)(bnShift + kk))[1];
                float sc8[8] = {s0[0], s0[1], s0[2], s0[3], s1v[0], s1v[1], s1v[2], s1v[3]};
                float sh8[8] = {h0[0], h0[1], h0[2], h0[3], h1[0], h1[1], h1[2], h1[3]};
#pragma unroll
                for (int mi = 0; mi < 2; mi++)
#pragma unroll
                    for (int j = 0; j < 8; j++) {
                        float f = fmaxf((float)af[mi][ks][j] * sc8[j] + sh8[j], 0.f);
                        af[mi][ks][j] = (bf16_t)f;
                    }
            }
        }
        f32x4 acc[2][NNI];
#pragma unroll
        for (int a = 0; a < 2; a++)
#pragma unroll
            for (int b = 0; b < NNI; b++) acc[a][b] = f32x4{0.f, 0.f, 0.f, 0.f};
#pragma unroll
        for (int ks = 0; ks < NKS; ks++)
#pragma unroll
            for (int ni = 0; ni < NNI; ni++) {
                acc[0][ni] = __builtin_amdgcn_mfma_f32_16x16x32_bf16(
                    af[0][ks], bfr[ni][ks], acc[0][ni], 0, 0, 0);
                acc[1][ni] = __builtin_amdgcn_mfma_f32_16x16x32_bf16(
                    af[1][ks], bfr[ni][ks], acc[1][ni], 0, 0, 0);
            }
        // per-tile epilogue
#pragma unroll
        for (int ni = 0; ni < NNI; ni++) {
            const int col = c0 + ni * 16 + lm;
#pragma unroll
            for (int mi = 0; mi < 2; mi++) {
#pragma unroll
                for (int r = 0; r < 4; r++) {
                    const int row = row0 + mi * 16 + q * 4 + r;
                    if (row < M) {
                        float v = acc[mi][ni][r] + bv[ni];
                        if (doStats) { st1[ni] += v; st2[ni] += v * v; }
                        if (doRelu) v = fmaxf(v, 0.f);
                        const size_t o = (size_t)row * NC + col;
                        if (outF) {
                            outF[o] = v;
                        } else {
                            if (doAccum) v += (float)outB[o];
                            outB[o] = (bf16_t)v;
                        }
                    }
                }
            }
        }
    }
    if (doStats) {
#pragma unroll
        for (int ni = 0; ni < NNI; ni++) {
            float s1 = st1[ni], s2 = st2[ni];
            s1 += __shfl_xor(s1, 16);
            s1 += __shfl_xor(s1, 32);
            s2 += __shfl_xor(s2, 16);
            s2 += __shfl_xor(s2, 32);
            if (q == 0) {
                atomicAdd(&colsum[c0 + ni * 16 + lm], s1);
                atomicAdd(&colsumsq[c0 + ni * 16 + lm], s2);
            }
        }
    }
}

// ---------------------------------------------------------------------------
extern "C" void kernel_launch(void* const* d_in, const int* in_sizes, int n_in,
                              void* d_out, int out_size, void* d_ws, size_t ws_size,
                              hipStream_t stream) {
    const float* x_in   = (const float*)d_in[0];
    const int*   ei     = (const int*)d_in[1];
    const int*   se0    = (const int*)d_in[2];
    const int*   se1    = (const int*)d_in[3];
    const float* msg_w1 = (const float*)d_in[4];
    const float* msg_b1 = (const float*)d_in[5];
    const float* bn_g   = (const float*)d_in[6];
    const float* bn_b   = (const float*)d_in[7];
    const float* msg_w2 = (const float*)d_in[8];
    const float* msg_b2 = (const float*)d_in[9];
    const float* eps_g  = (const float*)d_in[10];
    const float* n2s_w1 = (const float*)d_in[11];
    const float* n2s_b1 = (const float*)d_in[12];
    const float* n2s_w2 = (const float*)d_in[13];
    const float* n2s_b2 = (const float*)d_in[14];
    const float* s2n_w1 = (const float*)d_in[15];
    const float* s2n_b1 = (const float*)d_in[16];
    const float* s2n_w2 = (const float*)d_in[17];
    const float* s2n_b2 = (const float*)d_in[18];
    const float* out_w1 = (const float*)d_in[19];
    const float* out_b1 = (const float*)d_in[20];
    const float* out_w2 = (const float*)d_in[21];
    const float* out_b2 = (const float*)d_in[22];
    float* out = (float*)d_out;

    char* ws = (char*)d_ws;
    size_t off = 0;
    auto alloc = [&](size_t bytes) -> char* {
        char* p = ws + off;
        off += (bytes + 255) & ~(size_t)255;
        return p;
    };
    bf16_t* xbf   = (bf16_t*)alloc((size_t)N_NODES * HDIM * 2);   // residual x (bf16)
    bf16_t* xcomb = (bf16_t*)alloc((size_t)N_NODES * HDIM * 2);   // gin-comb / s2n msg
    bf16_t* hbuf  = (bf16_t*)alloc((size_t)N_NODES * H2DIM * 2);
    bf16_t* sxsum = (bf16_t*)alloc((size_t)NSUB_G * HDIM * 2);
    bf16_t* shbuf = (bf16_t*)alloc((size_t)NSUB_G * H2DIM * 2);
    bf16_t* sxout = (bf16_t*)alloc((size_t)NSUB_G * HDIM * 2);
    const size_t WSZ = (size_t)HDIM * H2DIM;
    bf16_t* wt_msg1 = (bf16_t*)alloc(NLAYER * WSZ * 2);
    bf16_t* wt_msg2 = (bf16_t*)alloc(NLAYER * WSZ * 2);
    bf16_t* wt_n2s1 = (bf16_t*)alloc(NLAYER * NSUBT * WSZ * 2);
    bf16_t* wt_n2s2 = (bf16_t*)alloc(NLAYER * NSUBT * WSZ * 2);
    bf16_t* wt_s2n1 = (bf16_t*)alloc(NLAYER * NSUBT * WSZ * 2);
    bf16_t* wt_s2n2 = (bf16_t*)alloc(NLAYER * NSUBT * WSZ * 2);
    bf16_t* wt_out1 = (bf16_t*)alloc(WSZ * 2);
    bf16_t* wt_out2 = (bf16_t*)alloc(WSZ * 2);
    float* colsum   = (float*)alloc(H2DIM * 4);
    float* colsumsq = (float*)alloc(H2DIM * 4);
    float* bnscale  = (float*)alloc(H2DIM * 4);
    float* bnshift  = (float*)alloc(H2DIM * 4);
    int* rp_gin   = (int*)alloc((N_NODES + 1) * 4);
    int* gat_gin  = (int*)alloc((size_t)E_EDGES * 4);
    int* rp_n2s0  = (int*)alloc((NSUB_G + 1) * 4);
    int* gat_n2s0 = (int*)alloc((size_t)ESUB_E * 4);
    int* rp_n2s1  = (int*)alloc((NSUB_G + 1) * 4);
    int* gat_n2s1 = (int*)alloc((size_t)ESUB_E * 4);
    int* rp_s2n0  = (int*)alloc((N_NODES + 1) * 4);
    int* gat_s2n0 = (int*)alloc((size_t)ESUB_E * 4);
    int* rp_s2n1  = (int*)alloc((N_NODES + 1) * 4);
    int* gat_s2n1 = (int*)alloc((size_t)ESUB_E * 4);
    int* counts  = (int*)alloc((N_NODES + 1) * 4);
    int* partial = (int*)alloc((size_t)N_NODES * 4);
    int* bsum    = (int*)alloc(512 * 4);
    (void)ws_size; (void)in_sizes; (void)n_in; (void)out_size;

    auto tr = [&](const float* W, bf16_t* Wt, int K, int Nc, int batch) {
        long total = (long)batch * K * Nc;
        int blocks = (int)((total + 255) / 256);
        transpose_w<<<blocks, 256, 0, stream>>>(W, Wt, K, Nc, total);
    };
    tr(msg_w1, wt_msg1, HDIM, H2DIM, NLAYER);
    tr(msg_w2, wt_msg2, H2DIM, HDIM, NLAYER);
    tr(n2s_w1, wt_n2s1, HDIM, H2DIM, NLAYER * NSUBT);
    tr(n2s_w2, wt_n2s2, H2DIM, HDIM, NLAYER * NSUBT);
    tr(s2n_w1, wt_s2n1, HDIM, H2DIM, NLAYER * NSUBT);
    tr(s2n_w2, wt_s2n2, H2DIM, HDIM, NLAYER * NSUBT);
    tr(out_w1, wt_out1, HDIM, H2DIM, 1);
    tr(out_w2, wt_out2, H2DIM, OUTD, 1);

    auto build_csr = [&](const int* idx, const int* gsrc, int nE, int nseg,
                         int* rowptr, int* gat) {
        hipMemsetAsync(counts, 0, (size_t)nseg * 4, stream);
        hist_k<<<(nE + 255) / 256, 256, 0, stream>>>(idx, counts, nE);
        int nb = (nseg + 1023) / 1024;
        scan1_k<<<nb, 256, 0, stream>>>(counts, partial, bsum, nseg);
        scan2_k<<<1, 256, 0, stream>>>(bsum, nb);
        scan3_k<<<(nseg + 255) / 256, 256, 0, stream>>>(partial, bsum, rowptr,
                                                        counts, nseg, nE);
        csr_place<<<(nE + 255) / 256, 256, 0, stream>>>(idx, gsrc, counts, gat, nE);
    };
    const int* src = ei;
    const int* dst = ei + E_EDGES;
    build_csr(dst, src, E_EDGES, N_NODES, rp_gin, gat_gin);
    build_csr(se0 + ESUB_E, se0, ESUB_E, NSUB_G, rp_n2s0, gat_n2s0);
    build_csr(se1 + ESUB_E, se1, ESUB_E, NSUB_G, rp_n2s1, gat_n2s1);
    build_csr(se0, se0 + ESUB_E, ESUB_E, N_NODES, rp_s2n0, gat_s2n0);
    build_csr(se1, se1 + ESUB_E, ESUB_E, N_NODES, rp_s2n1, gat_s2n1);

    {
        long n = (long)N_NODES * HDIM;
        cast_f2b<<<(int)((n / 4 + 255) / 256), 256, 0, stream>>>(x_in, xbf, n);
    }

    // gemm wrappers: K/NC compile-time (128,256) or (256,128)
    auto gemmA = [&](const bf16_t* Ab, const float* bnS, const float* bnH,
                     const bf16_t* Wt, const float* bias, int M,
                     bf16_t* oB, float* oF, float* cs, float* cs2,
                     int bnfold, int flags) {  // K=128, NC=256
        int nt = (M + 31) / 32;
        int g = nt < NBLK ? nt : NBLK;
        gemm_reg<128, 256><<<g, 256, 0, stream>>>(
            Ab, bnS, bnH, Wt, bias, M, oB, oF, cs, cs2, bnfold, flags);
    };
    auto gemmB = [&](const bf16_t* Ab, const float* bnS, const float* bnH,
                     const bf16_t* Wt, const float* bias, int M,
                     bf16_t* oB, float* oF, float* cs, float* cs2,
                     int bnfold, int flags) {  // K=256, NC=128
        int nt = (M + 31) / 32;
        int g = nt < NBLK ? nt : NBLK;
        gemm_reg<256, 128><<<g, 256, 0, stream>>>(
            Ab, bnS, bnH, Wt, bias, M, oB, oF, cs, cs2, bnfold, flags);
    };

    for (int i = 0; i < NLAYER; i++) {
        // GIN aggregation fused with (1+eps)x combine -> bf16
        segsum_ginb<<<(N_NODES + 3) / 4, 256, 0, stream>>>(
            xbf, eps_g + i, rp_gin, gat_gin, xcomb, N_NODES);
        // h = xcomb @ W1 + b1 ; column stats for BN
        hipMemsetAsync(colsum, 0, H2DIM * 4, stream);
        hipMemsetAsync(colsumsq, 0, H2DIM * 4, stream);
        gemmA(xcomb, nullptr, nullptr,
              wt_msg1 + (size_t)i * WSZ, msg_b1 + (size_t)i * H2DIM,
              N_NODES, hbuf, nullptr, colsum, colsumsq, 0, 4);
        bn_finalize<<<1, 256, 0, stream>>>(colsum, colsumsq, bn_g + (size_t)i * H2DIM,
                                           bn_b + (size_t)i * H2DIM, bnscale, bnshift,
                                           H2DIM, 1.0f / N_NODES);
        // x = relu(BN(h)) @ W2 + b2   (bf16)
        gemmB(hbuf, bnscale, bnshift,
              wt_msg2 + (size_t)i * WSZ, msg_b2 + (size_t)i * HDIM,
              N_NODES, xbf, nullptr, nullptr, nullptr, 1, 0);

        for (int s = 0; s < NSUBT; s++) {
            const int* rp_n2s = (s == 0 ? rp_n2s0 : rp_n2s1);
            const int* gt_n2s = (s == 0 ? gat_n2s0 : gat_n2s1);
            const int* rp_s2n = (s == 0 ? rp_s2n0 : rp_s2n1);
            const int* gt_s2n = (s == 0 ? gat_s2n0 : gat_s2n1);
            const size_t widx = ((size_t)i * NSUBT + s) * WSZ;
            const size_t b1o = ((size_t)i * NSUBT + s) * H2DIM;
            const size_t b2o = ((size_t)i * NSUBT + s) * HDIM;
            // sx = segment_sum(x[row], col)
            segsum_b16<<<(NSUB_G + 3) / 4, 256, 0, stream>>>(
                xbf, rp_n2s, gt_n2s, sxsum, NSUB_G);
            // sx = relu(sx@w1+b1)@w2+b2
            gemmA(sxsum, nullptr, nullptr, wt_n2s1 + widx, n2s_b1 + b1o,
                  NSUB_G, shbuf, nullptr, nullptr, nullptr, 0, 1);
            gemmB(shbuf, nullptr, nullptr, wt_n2s2 + widx, n2s_b2 + b2o,
                  NSUB_G, sxout, nullptr, nullptr, nullptr, 0, 0);
            // msg = segment_sum(sx[col], row)
            segsum_b16<<<(N_NODES + 3) / 4, 256, 0, stream>>>(
                sxout, rp_s2n, gt_s2n, xcomb, N_NODES);
            // x += relu(msg@w1+b1)@w2+b2
            gemmA(xcomb, nullptr, nullptr, wt_s2n1 + widx, s2n_b1 + b1o,
                  N_NODES, hbuf, nullptr, nullptr, nullptr, 0, 1);
            gemmB(hbuf, nullptr, nullptr, wt_s2n2 + widx, s2n_b2 + b2o,
                  N_NODES, xbf, nullptr, nullptr, nullptr, 0, 2);
        }
    }
    // output head
    gemmA(xbf, nullptr, nullptr, wt_out1, out_b1,
          N_NODES, hbuf, nullptr, nullptr, nullptr, 0, 1);
    gemmB(hbuf, nullptr, nullptr, wt_out2, out_b2,
          N_NODES, nullptr, out, nullptr, nullptr, 0, 0);
}